// Round 13
// baseline (184.073 us; speedup 1.0000x reference)
//
#include <hip/hip_runtime.h>

// LNCC loss: I,J [16,1,768,768] f32 -> out [16] f32
// R13: ring-retained 4-row batches. R12's win was bulk-issuing independent
// loads; its defects were (a) VGPR cap-squeeze spill (84 VGPR, 14.6MB scratch
// writes) and (b) every row loaded twice (in-row + out-row reload 8 rows
// later). Fix: the out-rows of step s ARE the in-rows of step s-2, so keep
// three 4-row batches A/B/C in registers and rotate statically (fully
// unrolled steps) -> 8 loads/step = the compulsory minimum, no reload.
// launch_bounds(256,3) caps at ~170 VGPR; demand ~155 -> no spill expected
// (WRITE_SIZE is the tell). Grid = 768 blocks = 3 blocks/CU at 3 waves/SIMD,
// no tail. Shuffle-hsum unchanged from R12.

constexpr int BATCH = 16;
constexpr int H = 768;
constexpr int W = 768;
constexpr float INV_WS = 1.0f / 81.0f;
constexpr float EPS = 3.0590232050182579e-07f;   // exp(-15)

constexpr int SEG = 16;                   // output rows per wave task
constexpr int NSEG = H / SEG;             // 48
constexpr int BANDW = 248;                // output cols per band
constexpr int NTHREADS = 256;             // 4 waves = 4 bands of one (seg,b)

__global__ void zero_acc_kernel(float* acc) {
    if (threadIdx.x < BATCH) acc[threadIdx.x] = 0.0f;
}

#define F4SCALE(a, s)  { a.x *= (s); a.y *= (s); a.z *= (s); a.w *= (s); }
#define F4ADD(a, u)    { a.x += u.x; a.y += u.y; a.z += u.z; a.w += u.w; }
#define F4SUB(a, u)    { a.x -= u.x; a.y -= u.y; a.z -= u.z; a.w -= u.w; }
#define F4FMA(a, u, v) { a.x = fmaf(u.x, v.x, a.x); a.y = fmaf(u.y, v.y, a.y); \
                         a.z = fmaf(u.z, v.z, a.z); a.w = fmaf(u.w, v.w, a.w); }
#define F4FMS(a, u, v) { a.x = fmaf(u.x, -v.x, a.x); a.y = fmaf(u.y, -v.y, a.y); \
                         a.z = fmaf(u.z, -v.z, a.z); a.w = fmaf(u.w, -v.w, a.w); }

// h[e] = sum of cs cols [c0+e, c0+e+8]; output col = c0+4+e = band*248+4*lane+e
#define HSUM_SHFL(c, h)                                                   \
    {                                                                     \
        const float s3 = c.w;                                             \
        const float s2 = c.w + c.z;                                       \
        const float s1 = s2 + c.y;                                        \
        const float s0 = s1 + c.x;          /* own total */               \
        const float p1 = c.x + c.y;                                       \
        const float p2 = p1 + c.z;                                        \
        const float pn = __shfl_down(s0, 1, 64);                          \
        const float q0 = __shfl_down(c.x, 2, 64);                         \
        const float q1 = __shfl_down(p1, 2, 64);                          \
        const float q2 = __shfl_down(p2, 2, 64);                          \
        const float q3 = __shfl_down(s0, 2, 64);                          \
        h[0] = s0 + pn + q0;                                              \
        h[1] = s1 + pn + q1;                                              \
        h[2] = s2 + pn + q2;                                              \
        h[3] = s3 + pn + q3;                                              \
    }

// one output row rr: in-add from raw (NIk,NJk), hsum+math, out-sub raw (OIk,OJk)
#define ROWC(NIk, NJk, OIk, OJk, rr)                                      \
    {                                                                     \
        const float si = ((rr) + 4 < H)  ? fm : 0.0f;                     \
        const float so = ((rr) - 4 >= 0) ? fm : 0.0f;                     \
        float4 vi = NIk, vj = NJk;                                        \
        F4SCALE(vi, si) F4SCALE(vj, si)                                   \
        F4ADD(cs0, vi) F4ADD(cs1, vj)                                     \
        F4FMA(cs2, vi, vi) F4FMA(cs3, vj, vj) F4FMA(cs4, vi, vj)          \
        float hI[4], hJ[4], hII[4], hJJ[4], hIJ[4];                       \
        HSUM_SHFL(cs0, hI)                                                \
        HSUM_SHFL(cs1, hJ)                                                \
        HSUM_SHFL(cs2, hII)                                               \
        HSUM_SHFL(cs3, hJJ)                                               \
        HSUM_SHFL(cs4, hIJ)                                               \
        float rowsum = 0.0f;                                              \
        _Pragma("unroll")                                                 \
        for (int e = 0; e < 4; ++e) {                                     \
            const float u = -hI[e] * INV_WS;                              \
            const float cross = fmaf(u, hJ[e], hIJ[e]);                   \
            const float Ivar  = fmaf(u, hI[e], hII[e]);                   \
            const float Jvar  = fmaf(-hJ[e] * INV_WS, hJ[e], hJJ[e]);     \
            float prod = Ivar * Jvar;                                     \
            float num  = cross * cross;                                   \
            if (!(prod > EPS)) { prod = 1.0f; num = 1.0f; }               \
            float inv_;                                                   \
            asm("v_rcp_f32 %0, %1" : "=v"(inv_) : "v"(prod + EPS));       \
            rowsum = fmaf(num, inv_, rowsum);                             \
        }                                                                 \
        accum += live ? rowsum : 0.0f;                                    \
        float4 oi = OIk, oj = OJk;                                        \
        F4SCALE(oi, so) F4SCALE(oj, so)                                   \
        F4SUB(cs0, oi) F4SUB(cs1, oj)                                     \
        F4FMS(cs2, oi, oi) F4FMS(cs3, oj, oj) F4FMS(cs4, oi, oj)          \
    }

// load 4 rows (rbase..rbase+3, clamped to [0, H-1]) into batch NN
#define LDBATCH(NI, NJ, rbase)                                            \
    {                                                                     \
        _Pragma("unroll")                                                 \
        for (int k = 0; k < 4; ++k) {                                     \
            const int rc = min(max((rbase) + k, 0), H - 1);               \
            NI[k] = *(const float4*)(Ib + (size_t)rc * W + ca);           \
            NJ[k] = *(const float4*)(Jb + (size_t)rc * W + ca);           \
        }                                                                 \
    }

// step: load NN = in-rows rr+4..rr+7, compute rows rr..rr+3 (out = PA,
// which holds raw rows rr-4..rr-1)
#define STEP(PAi, PAj, NNi, NNj, rr)                                      \
    LDBATCH(NNi, NNj, (rr) + 4)                                           \
    ROWC(NNi[0], NNj[0], PAi[0], PAj[0], (rr) + 0)                        \
    ROWC(NNi[1], NNj[1], PAi[1], PAj[1], (rr) + 1)                        \
    ROWC(NNi[2], NNj[2], PAi[2], PAj[2], (rr) + 2)                        \
    ROWC(NNi[3], NNj[3], PAi[3], PAj[3], (rr) + 3)

__launch_bounds__(NTHREADS, 3)
__global__ void lncc_ring3(const float* __restrict__ gI, const float* __restrict__ gJ,
                           float* __restrict__ acc)
{
    __shared__ float wsum[4];

    const int lane = threadIdx.x & 63;
    const int band = threadIdx.x >> 6;                   // 0..3
    const int r0   = blockIdx.x * SEG;
    const int b    = blockIdx.y;
    const int c0   = band * BANDW - 4 + 4 * lane;        // own cs base col
    const float fm = (c0 >= 0 && c0 + 3 < W) ? 1.0f : 0.0f;
    const int ca   = min(max(c0, 0), W - 4);             // 16B-aligned clamp
    const bool live = (lane <= 61) && (band * BANDW + 4 * lane + 3 < W);

    const float* __restrict__ Ib = gI + (size_t)b * (H * W);
    const float* __restrict__ Jb = gJ + (size_t)b * (H * W);

    float4 cs0 = {0,0,0,0}, cs1 = {0,0,0,0}, cs2 = {0,0,0,0},
           cs3 = {0,0,0,0}, cs4 = {0,0,0,0};

    float4 Ai[4], Aj[4], Bi[4], Bj[4], Ci[4], Cj[4];

    // ---- warm-up: A = raw rows r0-4..r0-1 (clamped), B = raw rows r0..r0+3
    LDBATCH(Ai, Aj, r0 - 4)
    LDBATCH(Bi, Bj, r0)

    #pragma unroll
    for (int k = 0; k < 4; ++k) {
        const float sm = (r0 - 4 + k >= 0) ? fm : 0.0f;
        float4 vi = Ai[k], vj = Aj[k];
        F4SCALE(vi, sm) F4SCALE(vj, sm)
        F4ADD(cs0, vi) F4ADD(cs1, vj)
        F4FMA(cs2, vi, vi) F4FMA(cs3, vj, vj) F4FMA(cs4, vi, vj)
    }
    #pragma unroll
    for (int k = 0; k < 4; ++k) {
        float4 vi = Bi[k], vj = Bj[k];
        F4SCALE(vi, fm) F4SCALE(vj, fm)
        F4ADD(cs0, vi) F4ADD(cs1, vj)
        F4FMA(cs2, vi, vi) F4FMA(cs3, vj, vj) F4FMA(cs4, vi, vj)
    }

    float accum = 0.0f;

    // ---- 4 statically-rotated steps of 4 rows (SEG = 16) ----
    STEP(Ai, Aj, Ci, Cj, r0)        // loads C = rows r0+4..7;   out = A
    STEP(Bi, Bj, Ai, Aj, r0 + 4)    // loads A = rows r0+8..11;  out = B
    STEP(Ci, Cj, Bi, Bj, r0 + 8)    // loads B = rows r0+12..15; out = C
    STEP(Ai, Aj, Ci, Cj, r0 + 12)   // loads C = rows r0+16..19 (clamped/masked
                                    //  at image bottom); out = A = rows r0+8..11

    // ---- wave reduce -> block reduce -> one atomic per block ----
    #pragma unroll
    for (int off = 32; off > 0; off >>= 1)
        accum += __shfl_xor(accum, off, 64);
    if (lane == 0) wsum[band] = accum;
    __syncthreads();
    if (threadIdx.x == 0)
        atomicAdd(&acc[b], wsum[0] + wsum[1] + wsum[2] + wsum[3]);
}

__global__ void finalize_kernel(const float* __restrict__ acc, float* __restrict__ out) {
    if (threadIdx.x < BATCH)
        out[threadIdx.x] = 1.0f - acc[threadIdx.x] * (1.0f / (float)(H * W));
}

extern "C" void kernel_launch(void* const* d_in, const int* in_sizes, int n_in,
                              void* d_out, int out_size, void* d_ws, size_t ws_size,
                              hipStream_t stream) {
    const float* I = (const float*)d_in[0];
    const float* J = (const float*)d_in[1];
    float* out = (float*)d_out;
    float* acc = (float*)d_ws;

    zero_acc_kernel<<<1, 64, 0, stream>>>(acc);

    dim3 grid(NSEG, BATCH);   // 48 x 16 = 768 blocks = exactly 3 blocks/CU
    lncc_ring3<<<grid, NTHREADS, 0, stream>>>(I, J, acc);

    finalize_kernel<<<1, 64, 0, stream>>>(acc, out);
}

// Round 14
// 42.445 us; speedup vs baseline: 4.3368x; 4.3368x over previous
//
#include <hip/hip_runtime.h>

// LNCC loss: I,J [16,1,768,768] f32 -> out [16] f32
// R14 = R12 (best: 45.3us) with ONLY launch_bounds changed (256,3)->(256,2).
// Empirical hipcc law from R6/R12/R13: VGPR cap ~= 256/arg2 for these blocks
// ((256,4)->64, (256,3)->84, (192,2) fit 120 under 128). R12's ~105-reg
// demand under an 85 cap caused its 14.6MB spill; (256,2) caps at 128 ->
// no spill, and 16 waves/CU residency still matches the 4096-wave grid.
// Structure: 4-row batched steps, bulk-issued independent loads, zero-
// redundancy register colsums, shuffle-tree horizontal 9-sums, no barriers.

constexpr int BATCH = 16;
constexpr int H = 768;
constexpr int W = 768;
constexpr float INV_WS = 1.0f / 81.0f;
constexpr float EPS = 3.0590232050182579e-07f;   // exp(-15)

constexpr int SEG = 12;                   // output rows per wave task
constexpr int NSEG = H / SEG;             // 64
constexpr int BANDW = 248;                // output cols per band
constexpr int NTHREADS = 256;             // 4 waves = 4 bands of one (seg,b)

__global__ void zero_acc_kernel(float* acc) {
    if (threadIdx.x < BATCH) acc[threadIdx.x] = 0.0f;
}

#define F4SCALE(a, s)  { a.x *= (s); a.y *= (s); a.z *= (s); a.w *= (s); }
#define F4ADD(a, u)    { a.x += u.x; a.y += u.y; a.z += u.z; a.w += u.w; }
#define F4SUB(a, u)    { a.x -= u.x; a.y -= u.y; a.z -= u.z; a.w -= u.w; }
#define F4FMA(a, u, v) { a.x = fmaf(u.x, v.x, a.x); a.y = fmaf(u.y, v.y, a.y); \
                         a.z = fmaf(u.z, v.z, a.z); a.w = fmaf(u.w, v.w, a.w); }
#define F4FMS(a, u, v) { a.x = fmaf(u.x, -v.x, a.x); a.y = fmaf(u.y, -v.y, a.y); \
                         a.z = fmaf(u.z, -v.z, a.z); a.w = fmaf(u.w, -v.w, a.w); }

// h[e] = sum of cs cols [c0+e, c0+e+8]; output col = c0+4+e = band*248+4*lane+e
#define HSUM_SHFL(c, h)                                                   \
    {                                                                     \
        const float s3 = c.w;                                             \
        const float s2 = c.w + c.z;                                       \
        const float s1 = s2 + c.y;                                        \
        const float s0 = s1 + c.x;          /* own total */               \
        const float p1 = c.x + c.y;                                       \
        const float p2 = p1 + c.z;                                        \
        const float pn = __shfl_down(s0, 1, 64);                          \
        const float q0 = __shfl_down(c.x, 2, 64);                         \
        const float q1 = __shfl_down(p1, 2, 64);                          \
        const float q2 = __shfl_down(p2, 2, 64);                          \
        const float q3 = __shfl_down(s0, 2, 64);                          \
        h[0] = s0 + pn + q0;                                              \
        h[1] = s1 + pn + q1;                                              \
        h[2] = s2 + pn + q2;                                              \
        h[3] = s3 + pn + q3;                                              \
    }

__launch_bounds__(NTHREADS, 2)
__global__ void lncc_b4(const float* __restrict__ gI, const float* __restrict__ gJ,
                        float* __restrict__ acc)
{
    __shared__ float wsum[4];

    const int lane = threadIdx.x & 63;
    const int band = threadIdx.x >> 6;                   // 0..3
    const int r0   = blockIdx.x * SEG;
    const int b    = blockIdx.y;
    const int c0   = band * BANDW - 4 + 4 * lane;        // own cs base col
    const float fm = (c0 >= 0 && c0 + 3 < W) ? 1.0f : 0.0f;
    const int ca   = min(max(c0, 0), W - 4);             // 16B-aligned clamp
    const bool live = (lane <= 61) && (band * BANDW + 4 * lane + 3 < W);

    const float* __restrict__ Ib = gI + (size_t)b * (H * W);
    const float* __restrict__ Jb = gJ + (size_t)b * (H * W);

    float4 cs0 = {0,0,0,0}, cs1 = {0,0,0,0}, cs2 = {0,0,0,0},
           cs3 = {0,0,0,0}, cs4 = {0,0,0,0};

    // ---- warm-up: rows r0-4 .. r0+3 in two bulk steps of 4 ----
    #pragma unroll
    for (int s = 0; s < 2; ++s) {
        float4 Vi[4], Vj[4];
        #pragma unroll
        for (int k = 0; k < 4; ++k) {
            const int rr = r0 - 4 + 4 * s + k;           // <= 759, never >= H
            const int rc = max(rr, 0);
            Vi[k] = *(const float4*)(Ib + (size_t)rc * W + ca);
            Vj[k] = *(const float4*)(Jb + (size_t)rc * W + ca);
        }
        #pragma unroll
        for (int k = 0; k < 4; ++k) {
            const float sm = (r0 - 4 + 4 * s + k >= 0) ? fm : 0.0f;
            float4 vi = Vi[k], vj = Vj[k];
            F4SCALE(vi, sm) F4SCALE(vj, sm)
            F4ADD(cs0, vi) F4ADD(cs1, vj)
            F4FMA(cs2, vi, vi) F4FMA(cs3, vj, vj) F4FMA(cs4, vi, vj)
        }
    }

    float accum = 0.0f;

    // ---- main loop: 3 steps of 4 output rows ----
    #pragma unroll 1
    for (int r = r0; r < r0 + SEG; r += 4) {
        // bulk-issue 16 independent loads for this step
        float4 Vi[4], Vj[4], Oi[4], Oj[4];
        #pragma unroll
        for (int k = 0; k < 4; ++k) {
            const int ri = min(r + 4 + k, H - 1);
            const int ro = max(r - 4 + k, 0);
            Vi[k] = *(const float4*)(Ib + (size_t)ri * W + ca);
            Vj[k] = *(const float4*)(Jb + (size_t)ri * W + ca);
            Oi[k] = *(const float4*)(Ib + (size_t)ro * W + ca);
            Oj[k] = *(const float4*)(Jb + (size_t)ro * W + ca);
        }

        // 4 rows of pure-VALU sliding-window compute
        #pragma unroll
        for (int k = 0; k < 4; ++k) {
            const float si = (r + 4 + k < H)  ? fm : 0.0f;
            const float so = (r - 4 + k >= 0) ? fm : 0.0f;

            float4 vi = Vi[k], vj = Vj[k];
            F4SCALE(vi, si) F4SCALE(vj, si)
            F4ADD(cs0, vi) F4ADD(cs1, vj)
            F4FMA(cs2, vi, vi) F4FMA(cs3, vj, vj) F4FMA(cs4, vi, vj)

            float hI[4], hJ[4], hII[4], hJJ[4], hIJ[4];
            HSUM_SHFL(cs0, hI)
            HSUM_SHFL(cs1, hJ)
            HSUM_SHFL(cs2, hII)
            HSUM_SHFL(cs3, hJJ)
            HSUM_SHFL(cs4, hIJ)

            float rowsum = 0.0f;
            #pragma unroll
            for (int e = 0; e < 4; ++e) {
                const float u = -hI[e] * INV_WS;
                const float cross = fmaf(u, hJ[e], hIJ[e]);
                const float Ivar  = fmaf(u, hI[e], hII[e]);
                const float Jvar  = fmaf(-hJ[e] * INV_WS, hJ[e], hJJ[e]);
                float prod = Ivar * Jvar;
                float num  = cross * cross;
                if (!(prod > EPS)) { prod = 1.0f; num = 1.0f; }
                float inv_;
                asm("v_rcp_f32 %0, %1" : "=v"(inv_) : "v"(prod + EPS));
                rowsum = fmaf(num, inv_, rowsum);
            }
            accum += live ? rowsum : 0.0f;

            float4 oi = Oi[k], oj = Oj[k];
            F4SCALE(oi, so) F4SCALE(oj, so)
            F4SUB(cs0, oi) F4SUB(cs1, oj)
            F4FMS(cs2, oi, oi) F4FMS(cs3, oj, oj) F4FMS(cs4, oi, oj)
        }
    }

    // ---- wave reduce -> block reduce -> one atomic per block ----
    #pragma unroll
    for (int off = 32; off > 0; off >>= 1)
        accum += __shfl_xor(accum, off, 64);
    if (lane == 0) wsum[band] = accum;
    __syncthreads();
    if (threadIdx.x == 0)
        atomicAdd(&acc[b], wsum[0] + wsum[1] + wsum[2] + wsum[3]);
}

__global__ void finalize_kernel(const float* __restrict__ acc, float* __restrict__ out) {
    if (threadIdx.x < BATCH)
        out[threadIdx.x] = 1.0f - acc[threadIdx.x] * (1.0f / (float)(H * W));
}

extern "C" void kernel_launch(void* const* d_in, const int* in_sizes, int n_in,
                              void* d_out, int out_size, void* d_ws, size_t ws_size,
                              hipStream_t stream) {
    const float* I = (const float*)d_in[0];
    const float* J = (const float*)d_in[1];
    float* out = (float*)d_out;
    float* acc = (float*)d_ws;

    zero_acc_kernel<<<1, 64, 0, stream>>>(acc);

    dim3 grid(NSEG, BATCH);   // 64 x 16 = 1024 blocks, 4096 waves = 16/CU
    lncc_b4<<<grid, NTHREADS, 0, stream>>>(I, J, acc);

    finalize_kernel<<<1, 64, 0, stream>>>(acc, out);
}